// Round 2
// 693.162 us; speedup vs baseline: 1.1009x; 1.1009x over previous
//
#include <hip/hip_runtime.h>
#include <hip/hip_bf16.h>
#include <math.h>

// Problem constants
#define DIM   1024
#define HEADS 16
#define DH    64
#define SEQ   2048
#define BATCH 4
#define ROWS  (BATCH * SEQ)      // 8192
#define MLP   4096
#define QKV3  (3 * DIM)          // 3072

typedef __bf16    bf16x8 __attribute__((ext_vector_type(8)));
typedef __bf16    bf16x4 __attribute__((ext_vector_type(4)));
typedef float     f32x4  __attribute__((ext_vector_type(4)));
typedef unsigned int u32x2 __attribute__((ext_vector_type(2)));

__device__ inline void store_out(float* p, float v)           { *p = v; }
__device__ inline void store_out(__hip_bfloat16* p, float v)  { *p = __float2bfloat16(v); }

// addrspace casts for global_load_lds (generic -> AS1/AS3 addrspacecast)
#define GLP(p) ((const __attribute__((address_space(1))) void*)(p))
#define LDP(p) ((__attribute__((address_space(3))) void*)(p))

// ---------------------------------------------------------------------------
// LayerNorm: fp32 in -> bf16 out. One block per row of 1024, 256 threads.
// ---------------------------------------------------------------------------
__global__ __launch_bounds__(256) void ln_kernel(
    const float* __restrict__ x,
    const float* __restrict__ g,
    const float* __restrict__ b,
    __hip_bfloat16* __restrict__ y)
{
    const int row = blockIdx.x;
    const int tid = threadIdx.x;
    __shared__ float red[256];

    const float* xr = x + (size_t)row * DIM;
    float vals[4];
    float s = 0.f;
#pragma unroll
    for (int i = 0; i < 4; ++i) {
        vals[i] = xr[tid + i * 256];
        s += vals[i];
    }
    red[tid] = s; __syncthreads();
    for (int t = 128; t > 0; t >>= 1) { if (tid < t) red[tid] += red[tid + t]; __syncthreads(); }
    const float mu = red[0] * (1.f / DIM);
    __syncthreads();

    float vs = 0.f;
#pragma unroll
    for (int i = 0; i < 4; ++i) { float d = vals[i] - mu; vs += d * d; }
    red[tid] = vs; __syncthreads();
    for (int t = 128; t > 0; t >>= 1) { if (tid < t) red[tid] += red[tid + t]; __syncthreads(); }
    const float rstd = rsqrtf(red[0] * (1.f / DIM) + 1e-5f);

#pragma unroll
    for (int i = 0; i < 4; ++i) {
        const int c = tid + i * 256;
        float o = (vals[i] - mu) * rstd * g[c] + b[c];
        y[(size_t)row * DIM + c] = __float2bfloat16(o);
    }
}

// ---------------------------------------------------------------------------
// Weight transpose+downcast: BT[n][k] (bf16) = B[r0+k][c0+n] (fp32).
// ---------------------------------------------------------------------------
__global__ __launch_bounds__(256) void transpose_w_kernel(
    const float* __restrict__ B, __bf16* __restrict__ BT,
    int Nfull, int r0, int c0, int Ksub)
{
    const int kb = blockIdx.x, nb = blockIdx.y;
    __shared__ float T[32][33];
    const int t  = threadIdx.x;
    const int r  = t >> 3;          // 0..31
    const int cq = (t & 7) * 4;     // 0..28

    f32x4 v = *(const f32x4*)(B + (size_t)(r0 + kb * 32 + r) * Nfull + c0 + nb * 32 + cq);
    T[r][cq] = v[0]; T[r][cq + 1] = v[1]; T[r][cq + 2] = v[2]; T[r][cq + 3] = v[3];
    __syncthreads();

    bf16x4 o;
#pragma unroll
    for (int i = 0; i < 4; ++i) o[i] = (__bf16)T[cq + i][r];
    *(bf16x4*)(BT + (size_t)(nb * 32 + r) * Ksub + kb * 32 + cq) = o;
}

// ---------------------------------------------------------------------------
// Tiled MFMA GEMM (unchanged, verified): C = act(A @ BT^T + bias) + res.
// Block = 128x128, 4 waves 2x2, each 64x64 (4x4 MFMA tiles), BK=32,
// staging via global_load_lds width=16.
// ---------------------------------------------------------------------------
template <typename OutT>
__global__ __launch_bounds__(256) void gemm_bt_kernel(
    const __bf16* __restrict__ A,
    const __bf16* __restrict__ BT,
    const float* __restrict__ bias,
    const float* __restrict__ res,
    OutT* __restrict__ C,
    int M, int N, int K, int do_gelu)
{
    __shared__ __align__(16) __bf16 As[128 * 32];
    __shared__ __align__(16) __bf16 Bs[128 * 32];

    const int tid  = threadIdx.x;
    const int lane = tid & 63;
    const int w    = tid >> 6;
    const int q    = lane >> 4;
    const int c    = lane & 15;
    const int mw   = (w >> 1) * 64;
    const int nw   = (w & 1) * 64;

    const int rowTile = blockIdx.y * 128;
    const int colTile = blockIdx.x * 128;

    const int j0   = 2 * w;
    const int sR0  = j0 * 16 + (lane >> 2);   // row for issue 0
    const int sK   = (lane & 3) * 8;
    const __bf16* Ap0 = A  + (size_t)(rowTile + sR0) * K + sK;
    const __bf16* Ap1 = A  + (size_t)(rowTile + sR0 + 16) * K + sK;
    const __bf16* Bp0 = BT + (size_t)(colTile + sR0) * K + sK;
    const __bf16* Bp1 = BT + (size_t)(colTile + sR0 + 16) * K + sK;
    __bf16* AsD0 = &As[(j0    ) * 512];
    __bf16* AsD1 = &As[(j0 + 1) * 512];
    __bf16* BsD0 = &Bs[(j0    ) * 512];
    __bf16* BsD1 = &Bs[(j0 + 1) * 512];

    f32x4 acc[4][4];
#pragma unroll
    for (int i = 0; i < 4; ++i)
#pragma unroll
        for (int j = 0; j < 4; ++j) acc[i][j] = (f32x4){0.f, 0.f, 0.f, 0.f};

    for (int k0 = 0; k0 < K; k0 += 32) {
        __builtin_amdgcn_global_load_lds(GLP(Ap0 + k0), LDP(AsD0), 16, 0, 0);
        __builtin_amdgcn_global_load_lds(GLP(Ap1 + k0), LDP(AsD1), 16, 0, 0);
        __builtin_amdgcn_global_load_lds(GLP(Bp0 + k0), LDP(BsD0), 16, 0, 0);
        __builtin_amdgcn_global_load_lds(GLP(Bp1 + k0), LDP(BsD1), 16, 0, 0);
        __syncthreads();

        bf16x8 af[4], bf[4];
#pragma unroll
        for (int mt = 0; mt < 4; ++mt)
            af[mt] = *(const bf16x8*)(&As[(mw + mt * 16 + c) * 32 + q * 8]);
#pragma unroll
        for (int nt = 0; nt < 4; ++nt)
            bf[nt] = *(const bf16x8*)(&Bs[(nw + nt * 16 + c) * 32 + q * 8]);

#pragma unroll
        for (int mt = 0; mt < 4; ++mt)
#pragma unroll
            for (int nt = 0; nt < 4; ++nt)
                acc[mt][nt] = __builtin_amdgcn_mfma_f32_16x16x32_bf16(af[mt], bf[nt], acc[mt][nt], 0, 0, 0);
        __syncthreads();
    }

#pragma unroll
    for (int nt = 0; nt < 4; ++nt) {
        const int col = colTile + nw + nt * 16 + c;
        const float bv = bias ? bias[col] : 0.f;
#pragma unroll
        for (int mt = 0; mt < 4; ++mt) {
#pragma unroll
            for (int r = 0; r < 4; ++r) {
                const int row = rowTile + mw + mt * 16 + q * 4 + r;
                float v = acc[mt][nt][r] + bv;
                if (do_gelu) v = 0.5f * v * (1.f + erff(v * 0.70710678118f));
                if (res) v += res[(size_t)row * N + col];
                store_out(&C[(size_t)row * N + col], v);
            }
        }
    }
}

// ---------------------------------------------------------------------------
// Flash attention v4 (round-2 of the LDS-op attack; NO tr-read, plain ops):
//  * Swapped QK^T: st = mfma(K_frag, Q_frag) -> S^T; lane (quad,c) holds P for
//    ONE query (c) at keys 16*kg + quad*4 + r. P fragments packed in registers
//    in keymap order: A-slot (quad,j) <-> key 32h + (j<4 ? quad*4+j
//    : 16+quad*4+(j-4)). Pt LDS round-trip deleted.
//  * V staged PRE-TRANSPOSED into permuted key order:
//      pos(key) = 32*(key>>5) + 8*((key&15)>>2) + 4*((key>>4)&1) + (key&3)
//    Vt[d][pos] pitch 72. PV B-fragment (h,quad) = ONE ds_read_b128 at
//    element d*72 + 32h + 8*quad  (verified by element-level examples).
//    Transpose happens at GLOBAL load: each thread gathers 8 rows x 1 dword
//    (2 d-columns, L1-resident lines) and writes 4x ds_write_b64. Zero scalar
//    LDS writes.
//  * 64 queries/wave (QB=256), KB=64: amortizes kf/bv LDS reads over 64 MFMA
//    per wave-tile. Grid = 8 x 16 x 4 = 512 blocks = 2 blocks/CU.
//  * T14 reg-staged prefetch of next tile; T5 setprio around MFMA clusters.
// ---------------------------------------------------------------------------
#define KB  64
#define QB  256
#define KTP 72
#define VTP 72
#define M0  8.0f
#define NT  (SEQ / KB)

__global__ __launch_bounds__(256, 2) void flash_attn_kernel(
    const __hip_bfloat16* __restrict__ qkv,
    __hip_bfloat16* __restrict__ out)
{
    const int tid  = threadIdx.x;
    const int w    = tid >> 6;
    const int lane = tid & 63;
    const int quad = lane >> 4;
    const int c    = lane & 15;

    const int h = blockIdx.y;
    const int b = blockIdx.z;
    const size_t base = (size_t)b * SEQ;
    const int qbase = blockIdx.x * QB + w * 64;

    __shared__ __align__(16) __bf16 Kt[KB * KTP];   // [key][d] pitch 72
    __shared__ __align__(16) __bf16 Vt[DH * VTP];   // [d][pos(key)] pitch 72

    const __bf16* qkvb = (const __bf16*)qkv;

    // Q fragments (B-operand of swapped QK^T): lane -> query qbase+qg*16+c,
    // d = kk*32 + quad*8 + j. Pre-scaled by dh^-0.5 = 0.125 (exact in bf16).
    bf16x8 aq[4][2];
#pragma unroll
    for (int qg = 0; qg < 4; ++qg)
#pragma unroll
        for (int kk = 0; kk < 2; ++kk) {
            bf16x8 t = *(const bf16x8*)(qkvb + (base + qbase + qg * 16 + c) * QKV3
                                        + h * DH + kk * 32 + quad * 8);
#pragma unroll
            for (int j = 0; j < 8; ++j) aq[qg][kk][j] = (__bf16)(0.125f * (float)t[j]);
        }

    f32x4 o[4][4];
#pragma unroll
    for (int qg = 0; qg < 4; ++qg)
#pragma unroll
        for (int ch = 0; ch < 4; ++ch) o[qg][ch] = (f32x4){0.f, 0.f, 0.f, 0.f};
    float l_lane[4] = {0.f, 0.f, 0.f, 0.f};

    // K staging map: thread -> rows sR, sR+32; d-chunk sD (8 wide), vector.
    const int sR = tid >> 3;          // 0..31
    const int sD = (tid & 7) * 8;     // 0..56
    const __bf16* Kg = qkvb + (base + sR) * QKV3 + DIM + h * DH + sD;

    // V gather map: thread -> key octet vm (rows 8vm..8vm+7), d-pair d0,d0+1.
    const int vm = tid & 7;
    const int d0 = (tid >> 3) * 2;    // 0..62
    const __bf16* Vg = qkvb + (base + 8 * vm) * QKV3 + 2 * DIM + h * DH + d0;
    // pos() base for this octet: keys 8vm+j land at bpos+{0..3} (j<4) and
    // bpos+8+{0..3} (j>=4).
    const int bpos = 32 * (vm >> 2) + 16 * (vm & 1) + 4 * ((vm >> 1) & 1);

    // T14 prologue: stage tile 0 into registers
    bf16x8 kA, kB_;
    unsigned vv[8];
    kA  = *(const bf16x8*)(Kg);
    kB_ = *(const bf16x8*)(Kg + (size_t)32 * QKV3);
#pragma unroll
    for (int j = 0; j < 8; ++j)
        vv[j] = *(const unsigned*)(Vg + (size_t)j * QKV3);

    for (int kt = 0; kt < NT; ++kt) {
        // ---- write staged registers to LDS (all vector writes)
        *(bf16x8*)(&Kt[sR * KTP + sD])        = kA;
        *(bf16x8*)(&Kt[(sR + 32) * KTP + sD]) = kB_;
        {
            const unsigned lo01 = (vv[0] & 0xFFFFu) | (vv[1] << 16);
            const unsigned lo23 = (vv[2] & 0xFFFFu) | (vv[3] << 16);
            const unsigned lo45 = (vv[4] & 0xFFFFu) | (vv[5] << 16);
            const unsigned lo67 = (vv[6] & 0xFFFFu) | (vv[7] << 16);
            const unsigned hi01 = (vv[0] >> 16) | (vv[1] & 0xFFFF0000u);
            const unsigned hi23 = (vv[2] >> 16) | (vv[3] & 0xFFFF0000u);
            const unsigned hi45 = (vv[4] >> 16) | (vv[5] & 0xFFFF0000u);
            const unsigned hi67 = (vv[6] >> 16) | (vv[7] & 0xFFFF0000u);
            *(u32x2*)(&Vt[(d0    ) * VTP + bpos])     = (u32x2){lo01, lo23};
            *(u32x2*)(&Vt[(d0    ) * VTP + bpos + 8]) = (u32x2){lo45, lo67};
            *(u32x2*)(&Vt[(d0 + 1) * VTP + bpos])     = (u32x2){hi01, hi23};
            *(u32x2*)(&Vt[(d0 + 1) * VTP + bpos + 8]) = (u32x2){hi45, hi67};
        }
        __syncthreads();

        // ---- T14: issue next tile's global loads now; consumed next iter
        if (kt + 1 < NT) {
            const size_t koff = (size_t)(kt + 1) * KB * QKV3;
            kA  = *(const bf16x8*)(Kg + koff);
            kB_ = *(const bf16x8*)(Kg + koff + (size_t)32 * QKV3);
#pragma unroll
            for (int j = 0; j < 8; ++j)
                vv[j] = *(const unsigned*)(Vg + koff + (size_t)j * QKV3);
        }

        // ---- K fragments (shared across all 4 query groups)
        bf16x8 kf[4][2];
#pragma unroll
        for (int kg = 0; kg < 4; ++kg)
#pragma unroll
            for (int kk = 0; kk < 2; ++kk)
                kf[kg][kk] = *(const bf16x8*)(&Kt[(kg * 16 + c) * KTP + kk * 32 + quad * 8]);

        // ---- QK^T (swapped) + softmax + in-register P, per query group
        bf16x8 ap[4][2];
#pragma unroll
        for (int qg = 0; qg < 4; ++qg) {
            f32x4 st[4];
#pragma unroll
            for (int kg = 0; kg < 4; ++kg) st[kg] = (f32x4){0.f, 0.f, 0.f, 0.f};
            __builtin_amdgcn_s_setprio(1);
#pragma unroll
            for (int kg = 0; kg < 4; ++kg)
#pragma unroll
                for (int kk = 0; kk < 2; ++kk)
                    st[kg] = __builtin_amdgcn_mfma_f32_16x16x32_bf16(kf[kg][kk], aq[qg][kk], st[kg], 0, 0, 0);
            __builtin_amdgcn_s_setprio(0);

            float s = 0.f;
#pragma unroll
            for (int kg = 0; kg < 4; ++kg)
#pragma unroll
                for (int r = 0; r < 4; ++r) {
                    const __bf16 pb = (__bf16)__expf(st[kg][r] - M0);
                    s += (float)pb;
                    ap[qg][kg >> 1][(kg & 1) * 4 + r] = pb;
                }
            l_lane[qg] += s;
        }

        // ---- PV: one b128 per B-fragment, reused across 4 query groups
        __builtin_amdgcn_s_setprio(1);
#pragma unroll
        for (int h2 = 0; h2 < 2; ++h2)
#pragma unroll
            for (int ch = 0; ch < 4; ++ch) {
                bf16x8 bv = *(const bf16x8*)(&Vt[(ch * 16 + c) * VTP + h2 * 32 + quad * 8]);
#pragma unroll
                for (int qg = 0; qg < 4; ++qg)
                    o[qg][ch] = __builtin_amdgcn_mfma_f32_16x16x32_bf16(ap[qg][h2], bv, o[qg][ch], 0, 0, 0);
            }
        __builtin_amdgcn_s_setprio(0);
        __syncthreads();
    }

    // ---- epilogue: lane (quad,c) holds l for query qg*16+c summed over its
    // key subset; quad-reduce then redistribute to the C/D row layout.
#pragma unroll
    for (int qg = 0; qg < 4; ++qg) {
        float l = l_lane[qg];
        l += __shfl_xor(l, 16, 64);
        l += __shfl_xor(l, 32, 64);
#pragma unroll
        for (int r = 0; r < 4; ++r) {
            const float inv = 1.f / __shfl(l, quad * 4 + r, 64);
            const size_t row = base + qbase + qg * 16 + quad * 4 + r;
#pragma unroll
            for (int ch = 0; ch < 4; ++ch)
                out[row * DIM + h * DH + ch * 16 + c] = __float2bfloat16(o[qg][ch][r] * inv);
        }
    }
}

// ---------------------------------------------------------------------------
// Launch. Workspace plan (peak 72 MiB):
//   X    [0,16):  bf16 8192x1024 — xn1 -> attnout -> xn2
//   wT   [16,24): bf16 transposed-weight slot, recycled 6x
//   qkv  [24,72): bf16 8192x3072 (dead after flash)
//   hdn  [24,56): bf16 8192x2048 (MLP half, reuses dead qkv; recycled 2x)
//   x1 lives in d_out (fp32); MLP split in halves, final GEMM accumulates
//   in-place.
// ---------------------------------------------------------------------------
extern "C" void kernel_launch(void* const* d_in, const int* in_sizes, int n_in,
                              void* d_out, int out_size, void* d_ws, size_t ws_size,
                              hipStream_t stream)
{
    const float* x     = (const float*)d_in[0];
    const float* ln1_g = (const float*)d_in[1];
    const float* ln1_b = (const float*)d_in[2];
    const float* w_qkv = (const float*)d_in[3];
    const float* w_out = (const float*)d_in[4];
    const float* b_out = (const float*)d_in[5];
    const float* ln2_g = (const float*)d_in[6];
    const float* ln2_b = (const float*)d_in[7];
    const float* w1    = (const float*)d_in[8];
    const float* b1    = (const float*)d_in[9];
    const float* w2    = (const float*)d_in[10];
    const float* b2    = (const float*)d_in[11];
    float* out = (float*)d_out;

    char* ws = (char*)d_ws;
    const size_t MiB = 1024 * 1024;
    __hip_bfloat16* X   = (__hip_bfloat16*)(ws);
    __bf16*         wT  = (__bf16*)(ws + 16 * MiB);
    __hip_bfloat16* qkv = (__hip_bfloat16*)(ws + 24 * MiB);
    __bf16*         hdn = (__bf16*)(ws + 24 * MiB);

    dim3 blk(256);

    // 1. wqkvT
    transpose_w_kernel<<<dim3(DIM / 32, QKV3 / 32), blk, 0, stream>>>(w_qkv, wT, QKV3, 0, 0, DIM);
    // 2. xn1 = LN1(x)
    ln_kernel<<<dim3(ROWS), blk, 0, stream>>>(x, ln1_g, ln1_b, X);
    // 3. qkv = xn1 @ w_qkv
    gemm_bt_kernel<__hip_bfloat16><<<dim3(QKV3 / 128, ROWS / 128), blk, 0, stream>>>(
        (const __bf16*)X, wT, nullptr, nullptr, qkv, ROWS, QKV3, DIM, 0);
    // 4. attnout = flash_attention(qkv) -> X
    flash_attn_kernel<<<dim3(SEQ / QB, HEADS, BATCH), blk, 0, stream>>>(qkv, X);
    // 5. woutT
    transpose_w_kernel<<<dim3(DIM / 32, DIM / 32), blk, 0, stream>>>(w_out, wT, DIM, 0, 0, DIM);
    // 6. x1 = x + attnout @ w_out + b_out -> d_out
    gemm_bt_kernel<float><<<dim3(DIM / 128, ROWS / 128), blk, 0, stream>>>(
        (const __bf16*)X, wT, b_out, x, out, ROWS, DIM, DIM, 0);
    // 7. xn2 = LN2(x1) -> X
    ln_kernel<<<dim3(ROWS), blk, 0, stream>>>(out, ln2_g, ln2_b, X);

    // MLP half A
    transpose_w_kernel<<<dim3(DIM / 32, 2048 / 32), blk, 0, stream>>>(w1, wT, MLP, 0, 0, DIM);
    gemm_bt_kernel<__hip_bfloat16><<<dim3(2048 / 128, ROWS / 128), blk, 0, stream>>>(
        (const __bf16*)X, wT, b1, nullptr, (__hip_bfloat16*)hdn, ROWS, 2048, DIM, 1);
    transpose_w_kernel<<<dim3(2048 / 32, DIM / 32), blk, 0, stream>>>(w2, wT, DIM, 0, 0, 2048);
    gemm_bt_kernel<float><<<dim3(DIM / 128, ROWS / 128), blk, 0, stream>>>(
        hdn, wT, b2, out, out, ROWS, DIM, 2048, 0);

    // MLP half B
    transpose_w_kernel<<<dim3(DIM / 32, 2048 / 32), blk, 0, stream>>>(w1, wT, MLP, 0, 2048, DIM);
    gemm_bt_kernel<__hip_bfloat16><<<dim3(2048 / 128, ROWS / 128), blk, 0, stream>>>(
        (const __bf16*)X, wT, b1 + 2048, nullptr, (__hip_bfloat16*)hdn, ROWS, 2048, DIM, 1);
    transpose_w_kernel<<<dim3(2048 / 32, DIM / 32), blk, 0, stream>>>(w2, wT, DIM, 2048, 0, 2048);
    gemm_bt_kernel<float><<<dim3(DIM / 128, ROWS / 128), blk, 0, stream>>>(
        hdn, wT, nullptr, out, out, ROWS, DIM, 2048, 0);
}

// Round 3
// 644.622 us; speedup vs baseline: 1.1838x; 1.0753x over previous
//
#include <hip/hip_runtime.h>
#include <hip/hip_bf16.h>
#include <math.h>

// Problem constants
#define DIM   1024
#define HEADS 16
#define DH    64
#define SEQ   2048
#define BATCH 4
#define ROWS  (BATCH * SEQ)      // 8192
#define MLP   4096
#define QKV3  (3 * DIM)          // 3072

typedef __bf16    bf16x8 __attribute__((ext_vector_type(8)));
typedef __bf16    bf16x4 __attribute__((ext_vector_type(4)));
typedef float     f32x4  __attribute__((ext_vector_type(4)));
typedef unsigned int u32x2 __attribute__((ext_vector_type(2)));

__device__ inline void store_out(float* p, float v)           { *p = v; }
__device__ inline void store_out(__hip_bfloat16* p, float v)  { *p = __float2bfloat16(v); }

// addrspace casts for global_load_lds (generic -> AS1/AS3 addrspacecast)
#define GLP(p) ((const __attribute__((address_space(1))) void*)(p))
#define LDP(p) ((__attribute__((address_space(3))) void*)(p))

__device__ inline float fast_exp2(float x) {
#if __has_builtin(__builtin_amdgcn_exp2f)
    return __builtin_amdgcn_exp2f(x);
#else
    return __expf(x * 0.69314718056f);
#endif
}

__device__ inline float fast_rcp(float x) {
#if __has_builtin(__builtin_amdgcn_rcpf)
    return __builtin_amdgcn_rcpf(x);
#else
    return 1.f / x;
#endif
}

// ---------------------------------------------------------------------------
// LayerNorm: fp32 in -> bf16 out. One block per row of 1024, 256 threads.
// ---------------------------------------------------------------------------
__global__ __launch_bounds__(256) void ln_kernel(
    const float* __restrict__ x,
    const float* __restrict__ g,
    const float* __restrict__ b,
    __hip_bfloat16* __restrict__ y)
{
    const int row = blockIdx.x;
    const int tid = threadIdx.x;
    __shared__ float red[256];

    const float* xr = x + (size_t)row * DIM;
    float vals[4];
    float s = 0.f;
#pragma unroll
    for (int i = 0; i < 4; ++i) {
        vals[i] = xr[tid + i * 256];
        s += vals[i];
    }
    red[tid] = s; __syncthreads();
    for (int t = 128; t > 0; t >>= 1) { if (tid < t) red[tid] += red[tid + t]; __syncthreads(); }
    const float mu = red[0] * (1.f / DIM);
    __syncthreads();

    float vs = 0.f;
#pragma unroll
    for (int i = 0; i < 4; ++i) { float d = vals[i] - mu; vs += d * d; }
    red[tid] = vs; __syncthreads();
    for (int t = 128; t > 0; t >>= 1) { if (tid < t) red[tid] += red[tid + t]; __syncthreads(); }
    const float rstd = rsqrtf(red[0] * (1.f / DIM) + 1e-5f);

#pragma unroll
    for (int i = 0; i < 4; ++i) {
        const int c = tid + i * 256;
        float o = (vals[i] - mu) * rstd * g[c] + b[c];
        y[(size_t)row * DIM + c] = __float2bfloat16(o);
    }
}

// ---------------------------------------------------------------------------
// Weight transpose+downcast: BT[n][k] (bf16) = B[r0+k][c0+n] (fp32).
// ---------------------------------------------------------------------------
__global__ __launch_bounds__(256) void transpose_w_kernel(
    const float* __restrict__ B, __bf16* __restrict__ BT,
    int Nfull, int r0, int c0, int Ksub)
{
    const int kb = blockIdx.x, nb = blockIdx.y;
    __shared__ float T[32][33];
    const int t  = threadIdx.x;
    const int r  = t >> 3;          // 0..31
    const int cq = (t & 7) * 4;     // 0..28

    f32x4 v = *(const f32x4*)(B + (size_t)(r0 + kb * 32 + r) * Nfull + c0 + nb * 32 + cq);
    T[r][cq] = v[0]; T[r][cq + 1] = v[1]; T[r][cq + 2] = v[2]; T[r][cq + 3] = v[3];
    __syncthreads();

    bf16x4 o;
#pragma unroll
    for (int i = 0; i < 4; ++i) o[i] = (__bf16)T[cq + i][r];
    *(bf16x4*)(BT + (size_t)(nb * 32 + r) * Ksub + kb * 32 + cq) = o;
}

// ---------------------------------------------------------------------------
// Tiled MFMA GEMM: C = act(A @ BT^T + bias) + res.
// Block = 128x128, 4 waves 2x2, each 64x64 (4x4 MFMA tiles), BK=32,
// staging via global_load_lds width=16.
// ROUND-3 CHANGE: GELU epilogue switched from erff (~25-30 VALU instr) to
// tanh-form via sigmoid identity gelu(v) ~= v * e/(e+1), e = exp(2*0.79788456*
// (v + 0.044715 v^3)) — ~7 instrs, max |delta| vs erf-GELU ~3e-4.
// y2 clamped at 80 to avoid inf*0 = NaN for pathological |v|>~10.
// ---------------------------------------------------------------------------
template <typename OutT>
__global__ __launch_bounds__(256) void gemm_bt_kernel(
    const __bf16* __restrict__ A,
    const __bf16* __restrict__ BT,
    const float* __restrict__ bias,
    const float* __restrict__ res,
    OutT* __restrict__ C,
    int M, int N, int K, int do_gelu)
{
    __shared__ __align__(16) __bf16 As[128 * 32];
    __shared__ __align__(16) __bf16 Bs[128 * 32];

    const int tid  = threadIdx.x;
    const int lane = tid & 63;
    const int w    = tid >> 6;
    const int q    = lane >> 4;
    const int c    = lane & 15;
    const int mw   = (w >> 1) * 64;
    const int nw   = (w & 1) * 64;

    const int rowTile = blockIdx.y * 128;
    const int colTile = blockIdx.x * 128;

    const int j0   = 2 * w;
    const int sR0  = j0 * 16 + (lane >> 2);   // row for issue 0
    const int sK   = (lane & 3) * 8;
    const __bf16* Ap0 = A  + (size_t)(rowTile + sR0) * K + sK;
    const __bf16* Ap1 = A  + (size_t)(rowTile + sR0 + 16) * K + sK;
    const __bf16* Bp0 = BT + (size_t)(colTile + sR0) * K + sK;
    const __bf16* Bp1 = BT + (size_t)(colTile + sR0 + 16) * K + sK;
    __bf16* AsD0 = &As[(j0    ) * 512];
    __bf16* AsD1 = &As[(j0 + 1) * 512];
    __bf16* BsD0 = &Bs[(j0    ) * 512];
    __bf16* BsD1 = &Bs[(j0 + 1) * 512];

    f32x4 acc[4][4];
#pragma unroll
    for (int i = 0; i < 4; ++i)
#pragma unroll
        for (int j = 0; j < 4; ++j) acc[i][j] = (f32x4){0.f, 0.f, 0.f, 0.f};

    for (int k0 = 0; k0 < K; k0 += 32) {
        __builtin_amdgcn_global_load_lds(GLP(Ap0 + k0), LDP(AsD0), 16, 0, 0);
        __builtin_amdgcn_global_load_lds(GLP(Ap1 + k0), LDP(AsD1), 16, 0, 0);
        __builtin_amdgcn_global_load_lds(GLP(Bp0 + k0), LDP(BsD0), 16, 0, 0);
        __builtin_amdgcn_global_load_lds(GLP(Bp1 + k0), LDP(BsD1), 16, 0, 0);
        __syncthreads();

        bf16x8 af[4], bf[4];
#pragma unroll
        for (int mt = 0; mt < 4; ++mt)
            af[mt] = *(const bf16x8*)(&As[(mw + mt * 16 + c) * 32 + q * 8]);
#pragma unroll
        for (int nt = 0; nt < 4; ++nt)
            bf[nt] = *(const bf16x8*)(&Bs[(nw + nt * 16 + c) * 32 + q * 8]);

#pragma unroll
        for (int mt = 0; mt < 4; ++mt)
#pragma unroll
            for (int nt = 0; nt < 4; ++nt)
                acc[mt][nt] = __builtin_amdgcn_mfma_f32_16x16x32_bf16(af[mt], bf[nt], acc[mt][nt], 0, 0, 0);
        __syncthreads();
    }

#pragma unroll
    for (int nt = 0; nt < 4; ++nt) {
        const int col = colTile + nw + nt * 16 + c;
        const float bv = bias ? bias[col] : 0.f;
#pragma unroll
        for (int mt = 0; mt < 4; ++mt) {
#pragma unroll
            for (int r = 0; r < 4; ++r) {
                const int row = rowTile + mw + mt * 16 + q * 4 + r;
                float v = acc[mt][nt][r] + bv;
                if (do_gelu) {
                    const float y2 = fminf(1.5957691216057308f * v * (1.f + 0.044715f * v * v), 80.f);
                    const float e  = __expf(y2);
                    v = v * e * fast_rcp(e + 1.f);
                }
                if (res) v += res[(size_t)row * N + col];
                store_out(&C[(size_t)row * N + col], v);
            }
        }
    }
}

// ---------------------------------------------------------------------------
// Flash attention v5 (round-3: softmax arithmetic cuts on the verified v4):
//  * Swapped QK^T: st = mfma(K_frag, Q_frag) -> S^T; lane (quad,c) holds P for
//    ONE query (c) at keys 16*kg + quad*4 + r. P fragments packed in registers.
//  * ROUND-3a: Q prescaled by 0.125*log2(e) (fp32 mul before bf16 round) and
//    st accumulators INITIALIZED to -M0*log2(e) -> P = exp2(st) directly.
//    Deletes 64 muls + 64 subs per lane-tile vs __expf(st - M0).
//  * ROUND-3b: l computed via MFMA with a ones-B-fragment:
//    ol[qg] += mfma(ap[qg][h], ones). D[row=query][col] puts l for query
//    quad*4+r in reg r — lane-local exactly where output rows live; deletes
//    64 adds/lane-tile AND the epilogue shuffle-reduce.
//  * V staged PRE-TRANSPOSED (pos(key) permuted order, pitch 72); PV
//    B-fragment = one ds_read_b128. K pitch 72. All-vector LDS writes.
//  * 64 queries/wave (QB=256), KB=64; T14 reg-staged prefetch; T5 setprio.
// ---------------------------------------------------------------------------
#define KB  64
#define QB  256
#define KTP 72
#define VTP 72
#define NT  (SEQ / KB)
// -M0 * log2(e), M0 = 8
#define NEG_M0_LOG2E  (-11.541560327111707f)
// 0.125 * log2(e)
#define QSCALE_LOG2E  (0.18033688011112043f)

__global__ __launch_bounds__(256, 2) void flash_attn_kernel(
    const __hip_bfloat16* __restrict__ qkv,
    __hip_bfloat16* __restrict__ out)
{
    const int tid  = threadIdx.x;
    const int w    = tid >> 6;
    const int lane = tid & 63;
    const int quad = lane >> 4;
    const int c    = lane & 15;

    const int h = blockIdx.y;
    const int b = blockIdx.z;
    const size_t base = (size_t)b * SEQ;
    const int qbase = blockIdx.x * QB + w * 64;

    __shared__ __align__(16) __bf16 Kt[KB * KTP];   // [key][d] pitch 72
    __shared__ __align__(16) __bf16 Vt[DH * VTP];   // [d][pos(key)] pitch 72

    const __bf16* qkvb = (const __bf16*)qkv;

    // Q fragments (B-operand of swapped QK^T): lane -> query qbase+qg*16+c,
    // d = kk*32 + quad*8 + j. Pre-scaled by 0.125*log2(e).
    bf16x8 aq[4][2];
#pragma unroll
    for (int qg = 0; qg < 4; ++qg)
#pragma unroll
        for (int kk = 0; kk < 2; ++kk) {
            bf16x8 t = *(const bf16x8*)(qkvb + (base + qbase + qg * 16 + c) * QKV3
                                        + h * DH + kk * 32 + quad * 8);
#pragma unroll
            for (int j = 0; j < 8; ++j) aq[qg][kk][j] = (__bf16)(QSCALE_LOG2E * (float)t[j]);
        }

    bf16x8 onesv;
#pragma unroll
    for (int j = 0; j < 8; ++j) onesv[j] = (__bf16)1.0f;

    f32x4 o[4][4];
#pragma unroll
    for (int qg = 0; qg < 4; ++qg)
#pragma unroll
        for (int ch = 0; ch < 4; ++ch) o[qg][ch] = (f32x4){0.f, 0.f, 0.f, 0.f};
    f32x4 ol[4] = {{0,0,0,0},{0,0,0,0},{0,0,0,0},{0,0,0,0}};

    // K staging map: thread -> rows sR, sR+32; d-chunk sD (8 wide), vector.
    const int sR = tid >> 3;          // 0..31
    const int sD = (tid & 7) * 8;     // 0..56
    const __bf16* Kg = qkvb + (base + sR) * QKV3 + DIM + h * DH + sD;

    // V gather map: thread -> key octet vm (rows 8vm..8vm+7), d-pair d0,d0+1.
    const int vm = tid & 7;
    const int d0 = (tid >> 3) * 2;    // 0..62
    const __bf16* Vg = qkvb + (base + 8 * vm) * QKV3 + 2 * DIM + h * DH + d0;
    const int bpos = 32 * (vm >> 2) + 16 * (vm & 1) + 4 * ((vm >> 1) & 1);

    // T14 prologue: stage tile 0 into registers
    bf16x8 kA, kB_;
    unsigned vv[8];
    kA  = *(const bf16x8*)(Kg);
    kB_ = *(const bf16x8*)(Kg + (size_t)32 * QKV3);
#pragma unroll
    for (int j = 0; j < 8; ++j)
        vv[j] = *(const unsigned*)(Vg + (size_t)j * QKV3);

    for (int kt = 0; kt < NT; ++kt) {
        // ---- write staged registers to LDS (all vector writes)
        *(bf16x8*)(&Kt[sR * KTP + sD])        = kA;
        *(bf16x8*)(&Kt[(sR + 32) * KTP + sD]) = kB_;
        {
            const unsigned lo01 = (vv[0] & 0xFFFFu) | (vv[1] << 16);
            const unsigned lo23 = (vv[2] & 0xFFFFu) | (vv[3] << 16);
            const unsigned lo45 = (vv[4] & 0xFFFFu) | (vv[5] << 16);
            const unsigned lo67 = (vv[6] & 0xFFFFu) | (vv[7] << 16);
            const unsigned hi01 = (vv[0] >> 16) | (vv[1] & 0xFFFF0000u);
            const unsigned hi23 = (vv[2] >> 16) | (vv[3] & 0xFFFF0000u);
            const unsigned hi45 = (vv[4] >> 16) | (vv[5] & 0xFFFF0000u);
            const unsigned hi67 = (vv[6] >> 16) | (vv[7] & 0xFFFF0000u);
            *(u32x2*)(&Vt[(d0    ) * VTP + bpos])     = (u32x2){lo01, lo23};
            *(u32x2*)(&Vt[(d0    ) * VTP + bpos + 8]) = (u32x2){lo45, lo67};
            *(u32x2*)(&Vt[(d0 + 1) * VTP + bpos])     = (u32x2){hi01, hi23};
            *(u32x2*)(&Vt[(d0 + 1) * VTP + bpos + 8]) = (u32x2){hi45, hi67};
        }
        __syncthreads();

        // ---- T14: issue next tile's global loads now; consumed next iter
        if (kt + 1 < NT) {
            const size_t koff = (size_t)(kt + 1) * KB * QKV3;
            kA  = *(const bf16x8*)(Kg + koff);
            kB_ = *(const bf16x8*)(Kg + koff + (size_t)32 * QKV3);
#pragma unroll
            for (int j = 0; j < 8; ++j)
                vv[j] = *(const unsigned*)(Vg + koff + (size_t)j * QKV3);
        }

        // ---- K fragments (shared across all 4 query groups)
        bf16x8 kf[4][2];
#pragma unroll
        for (int kg = 0; kg < 4; ++kg)
#pragma unroll
            for (int kk = 0; kk < 2; ++kk)
                kf[kg][kk] = *(const bf16x8*)(&Kt[(kg * 16 + c) * KTP + kk * 32 + quad * 8]);

        // ---- QK^T (swapped) + softmax + in-register P, per query group
        bf16x8 ap[4][2];
#pragma unroll
        for (int qg = 0; qg < 4; ++qg) {
            f32x4 st[4];
#pragma unroll
            for (int kg = 0; kg < 4; ++kg)
                st[kg] = (f32x4){NEG_M0_LOG2E, NEG_M0_LOG2E, NEG_M0_LOG2E, NEG_M0_LOG2E};
            __builtin_amdgcn_s_setprio(1);
#pragma unroll
            for (int kg = 0; kg < 4; ++kg)
#pragma unroll
                for (int kk = 0; kk < 2; ++kk)
                    st[kg] = __builtin_amdgcn_mfma_f32_16x16x32_bf16(kf[kg][kk], aq[qg][kk], st[kg], 0, 0, 0);
            __builtin_amdgcn_s_setprio(0);

#pragma unroll
            for (int kg = 0; kg < 4; ++kg)
#pragma unroll
                for (int r = 0; r < 4; ++r)
                    ap[qg][kg >> 1][(kg & 1) * 4 + r] = (__bf16)fast_exp2(st[kg][r]);
        }

        // ---- PV (+ l-accumulation via ones-fragment MFMA)
        __builtin_amdgcn_s_setprio(1);
#pragma unroll
        for (int qg = 0; qg < 4; ++qg) {
            ol[qg] = __builtin_amdgcn_mfma_f32_16x16x32_bf16(ap[qg][0], onesv, ol[qg], 0, 0, 0);
            ol[qg] = __builtin_amdgcn_mfma_f32_16x16x32_bf16(ap[qg][1], onesv, ol[qg], 0, 0, 0);
        }
#pragma unroll
        for (int h2 = 0; h2 < 2; ++h2)
#pragma unroll
            for (int ch = 0; ch < 4; ++ch) {
                bf16x8 bv = *(const bf16x8*)(&Vt[(ch * 16 + c) * VTP + h2 * 32 + quad * 8]);
#pragma unroll
                for (int qg = 0; qg < 4; ++qg)
                    o[qg][ch] = __builtin_amdgcn_mfma_f32_16x16x32_bf16(ap[qg][h2], bv, o[qg][ch], 0, 0, 0);
            }
        __builtin_amdgcn_s_setprio(0);
        __syncthreads();
    }

    // ---- epilogue: ol[qg][r] = l for query quad*4+r of group qg (lane-local).
#pragma unroll
    for (int qg = 0; qg < 4; ++qg) {
#pragma unroll
        for (int r = 0; r < 4; ++r) {
            const float inv = 1.f / ol[qg][r];
            const size_t row = base + qbase + qg * 16 + quad * 4 + r;
#pragma unroll
            for (int ch = 0; ch < 4; ++ch)
                out[row * DIM + h * DH + ch * 16 + c] = __float2bfloat16(o[qg][ch][r] * inv);
        }
    }
}

// ---------------------------------------------------------------------------
// Launch. Workspace plan (peak 72 MiB):
//   X    [0,16):  bf16 8192x1024 — xn1 -> attnout -> xn2
//   wT   [16,24): bf16 transposed-weight slot, recycled 6x
//   qkv  [24,72): bf16 8192x3072 (dead after flash)
//   hdn  [24,56): bf16 8192x2048 (MLP half, reuses dead qkv; recycled 2x)
//   x1 lives in d_out (fp32); MLP split in halves, final GEMM accumulates
//   in-place.
// ---------------------------------------------------------------------------
extern "C" void kernel_launch(void* const* d_in, const int* in_sizes, int n_in,
                              void* d_out, int out_size, void* d_ws, size_t ws_size,
                              hipStream_t stream)
{
    const float* x     = (const float*)d_in[0];
    const float* ln1_g = (const float*)d_in[1];
    const float* ln1_b = (const float*)d_in[2];
    const float* w_qkv = (const float*)d_in[3];
    const float* w_out = (const float*)d_in[4];
    const float* b_out = (const float*)d_in[5];
    const float* ln2_g = (const float*)d_in[6];
    const float* ln2_b = (const float*)d_in[7];
    const float* w1    = (const float*)d_in[8];
    const float* b1    = (const float*)d_in[9];
    const float* w2    = (const float*)d_in[10];
    const float* b2    = (const float*)d_in[11];
    float* out = (float*)d_out;

    char* ws = (char*)d_ws;
    const size_t MiB = 1024 * 1024;
    __hip_bfloat16* X   = (__hip_bfloat16*)(ws);
    __bf16*         wT  = (__bf16*)(ws + 16 * MiB);
    __hip_bfloat16* qkv = (__hip_bfloat16*)(ws + 24 * MiB);
    __bf16*         hdn = (__bf16*)(ws + 24 * MiB);

    dim3 blk(256);

    // 1. wqkvT
    transpose_w_kernel<<<dim3(DIM / 32, QKV3 / 32), blk, 0, stream>>>(w_qkv, wT, QKV3, 0, 0, DIM);
    // 2. xn1 = LN1(x)
    ln_kernel<<<dim3(ROWS), blk, 0, stream>>>(x, ln1_g, ln1_b, X);
    // 3. qkv = xn1 @ w_qkv
    gemm_bt_kernel<__hip_bfloat16><<<dim3(QKV3 / 128, ROWS / 128), blk, 0, stream>>>(
        (const __bf16*)X, wT, nullptr, nullptr, qkv, ROWS, QKV3, DIM, 0);
    // 4. attnout = flash_attention(qkv) -> X
    flash_attn_kernel<<<dim3(SEQ / QB, HEADS, BATCH), blk, 0, stream>>>(qkv, X);
    // 5. woutT
    transpose_w_kernel<<<dim3(DIM / 32, DIM / 32), blk, 0, stream>>>(w_out, wT, DIM, 0, 0, DIM);
    // 6. x1 = x + attnout @ w_out + b_out -> d_out
    gemm_bt_kernel<float><<<dim3(DIM / 128, ROWS / 128), blk, 0, stream>>>(
        (const __bf16*)X, wT, b_out, x, out, ROWS, DIM, DIM, 0);
    // 7. xn2 = LN2(x1) -> X
    ln_kernel<<<dim3(ROWS), blk, 0, stream>>>(out, ln2_g, ln2_b, X);

    // MLP half A
    transpose_w_kernel<<<dim3(DIM / 32, 2048 / 32), blk, 0, stream>>>(w1, wT, MLP, 0, 0, DIM);
    gemm_bt_kernel<__hip_bfloat16><<<dim3(2048 / 128, ROWS / 128), blk, 0, stream>>>(
        (const __bf16*)X, wT, b1, nullptr, (__hip_bfloat16*)hdn, ROWS, 2048, DIM, 1);
    transpose_w_kernel<<<dim3(2048 / 32, DIM / 32), blk, 0, stream>>>(w2, wT, DIM, 0, 0, 2048);
    gemm_bt_kernel<float><<<dim3(DIM / 128, ROWS / 128), blk, 0, stream>>>(
        hdn, wT, b2, out, out, ROWS, DIM, 2048, 0);

    // MLP half B
    transpose_w_kernel<<<dim3(DIM / 32, 2048 / 32), blk, 0, stream>>>(w1, wT, MLP, 0, 2048, DIM);
    gemm_bt_kernel<__hip_bfloat16><<<dim3(2048 / 128, ROWS / 128), blk, 0, stream>>>(
        (const __bf16*)X, wT, b1 + 2048, nullptr, (__hip_bfloat16*)hdn, ROWS, 2048, DIM, 1);
    transpose_w_kernel<<<dim3(2048 / 32, DIM / 32), blk, 0, stream>>>(w2, wT, DIM, 2048, 0, 2048);
    gemm_bt_kernel<float><<<dim3(DIM / 128, ROWS / 128), blk, 0, stream>>>(
        hdn, wT, nullptr, out, out, ROWS, DIM, 2048, 0);
}

// Round 4
// 602.157 us; speedup vs baseline: 1.2672x; 1.0705x over previous
//
#include <hip/hip_runtime.h>
#include <hip/hip_bf16.h>
#include <math.h>

// Problem constants
#define DIM   1024
#define HEADS 16
#define DH    64
#define SEQ   2048
#define BATCH 4
#define ROWS  (BATCH * SEQ)      // 8192
#define MLP   4096
#define QKV3  (3 * DIM)          // 3072

typedef __bf16    bf16x8 __attribute__((ext_vector_type(8)));
typedef __bf16    bf16x4 __attribute__((ext_vector_type(4)));
typedef float     f32x4  __attribute__((ext_vector_type(4)));
typedef unsigned int u32x2 __attribute__((ext_vector_type(2)));

__device__ inline void store_out(float* p, float v)           { *p = v; }
__device__ inline void store_out(__hip_bfloat16* p, float v)  { *p = __float2bfloat16(v); }

// addrspace casts for global_load_lds (generic -> AS1/AS3 addrspacecast)
#define GLP(p) ((const __attribute__((address_space(1))) void*)(p))
#define LDP(p) ((__attribute__((address_space(3))) void*)(p))

__device__ inline float fast_exp2(float x) {
#if __has_builtin(__builtin_amdgcn_exp2f)
    return __builtin_amdgcn_exp2f(x);
#else
    return __expf(x * 0.69314718056f);
#endif
}

__device__ inline float fast_rcp(float x) {
#if __has_builtin(__builtin_amdgcn_rcpf)
    return __builtin_amdgcn_rcpf(x);
#else
    return 1.f / x;
#endif
}

// ---------------------------------------------------------------------------
// LayerNorm: fp32 in -> bf16 out. One block per row of 1024, 256 threads.
// ---------------------------------------------------------------------------
__global__ __launch_bounds__(256) void ln_kernel(
    const float* __restrict__ x,
    const float* __restrict__ g,
    const float* __restrict__ b,
    __hip_bfloat16* __restrict__ y)
{
    const int row = blockIdx.x;
    const int tid = threadIdx.x;
    __shared__ float red[256];

    const float* xr = x + (size_t)row * DIM;
    float vals[4];
    float s = 0.f;
#pragma unroll
    for (int i = 0; i < 4; ++i) {
        vals[i] = xr[tid + i * 256];
        s += vals[i];
    }
    red[tid] = s; __syncthreads();
    for (int t = 128; t > 0; t >>= 1) { if (tid < t) red[tid] += red[tid + t]; __syncthreads(); }
    const float mu = red[0] * (1.f / DIM);
    __syncthreads();

    float vs = 0.f;
#pragma unroll
    for (int i = 0; i < 4; ++i) { float d = vals[i] - mu; vs += d * d; }
    red[tid] = vs; __syncthreads();
    for (int t = 128; t > 0; t >>= 1) { if (tid < t) red[tid] += red[tid + t]; __syncthreads(); }
    const float rstd = rsqrtf(red[0] * (1.f / DIM) + 1e-5f);

#pragma unroll
    for (int i = 0; i < 4; ++i) {
        const int c = tid + i * 256;
        float o = (vals[i] - mu) * rstd * g[c] + b[c];
        y[(size_t)row * DIM + c] = __float2bfloat16(o);
    }
}

// ---------------------------------------------------------------------------
// Weight transpose+downcast: BT[n][k] (bf16) = B[r0+k][c0+n] (fp32).
// ---------------------------------------------------------------------------
__global__ __launch_bounds__(256) void transpose_w_kernel(
    const float* __restrict__ B, __bf16* __restrict__ BT,
    int Nfull, int r0, int c0, int Ksub)
{
    const int kb = blockIdx.x, nb = blockIdx.y;
    __shared__ float T[32][33];
    const int t  = threadIdx.x;
    const int r  = t >> 3;          // 0..31
    const int cq = (t & 7) * 4;     // 0..28

    f32x4 v = *(const f32x4*)(B + (size_t)(r0 + kb * 32 + r) * Nfull + c0 + nb * 32 + cq);
    T[r][cq] = v[0]; T[r][cq + 1] = v[1]; T[r][cq + 2] = v[2]; T[r][cq + 3] = v[3];
    __syncthreads();

    bf16x4 o;
#pragma unroll
    for (int i = 0; i < 4; ++i) o[i] = (__bf16)T[cq + i][r];
    *(bf16x4*)(BT + (size_t)(nb * 32 + r) * Ksub + kb * 32 + cq) = o;
}

// ---------------------------------------------------------------------------
// Tiled MFMA GEMM v3 (ROUND-4): C = act(A @ BT^T + bias) + res.
// Block = 256x128, 512 threads, 8 waves 4x2, each 64x64 (4x4 MFMA tiles),
// BK=32. T3 "minimum 2-phase" structure: double-buffered LDS, stage-EARLY
// (next tile's global_load_lds issued before this tile's compute), ONE
// __syncthreads per iteration (its implicit vmcnt(0)+lgkmcnt(0) drain covers
// next-tile loads, which had the whole compute phase to fly).
// Race ledger: buf[n] written at iter t -> drained+barriered at end of t ->
// read at iter t+1 -> all reads lgkm-drained before t+1's trailing barrier ->
// rewritten at t+2. Every write/read pair separated by exactly one barrier.
// 256x128 tile: 85 FLOP/staged-byte (vs 65 at 128^2) -> -23% L2/L3 traffic.
// ---------------------------------------------------------------------------
template <typename OutT>
__global__ __launch_bounds__(512, 3) void gemm_bt_kernel(
    const __bf16* __restrict__ A,
    const __bf16* __restrict__ BT,
    const float* __restrict__ bias,
    const float* __restrict__ res,
    OutT* __restrict__ C,
    int M, int N, int K, int do_gelu)
{
    __shared__ __align__(16) __bf16 As[2][256 * 32];
    __shared__ __align__(16) __bf16 Bs[2][128 * 32];

    const int tid  = threadIdx.x;
    const int lane = tid & 63;
    const int w    = tid >> 6;        // 0..7
    const int q    = lane >> 4;
    const int c    = lane & 15;
    const int mw   = (w >> 1) * 64;   // wave row: 0,64,128,192
    const int nw   = (w & 1) * 64;    // wave col: 0,64

    const int rowTile = blockIdx.y * 256;
    const int colTile = blockIdx.x * 128;

    // Staging map (512 threads): thread covers row tid>>2, k-chunk (tid&3)*8.
    // A tile 256x32 = 2 issues (rows 0..127, 128..255); B tile 128x32 = 1.
    // LDS elem offset = (tid>>2)*32 + (tid&3)*8 = tid*8 -> linear; per-wave
    // dst base = w*512 elems (gload_lds: wave-uniform base + lane*16B).
    const int sRow = tid >> 2;        // 0..127
    const int sK   = (tid & 3) * 8;
    const __bf16* Ap0 = A  + (size_t)(rowTile + sRow) * K + sK;
    const __bf16* Ap1 = A  + (size_t)(rowTile + 128 + sRow) * K + sK;
    const __bf16* Bp  = BT + (size_t)(colTile + sRow) * K + sK;
    const int wd = w * 512;           // per-wave LDS base (elems)

    f32x4 acc[4][4];
#pragma unroll
    for (int i = 0; i < 4; ++i)
#pragma unroll
        for (int j = 0; j < 4; ++j) acc[i][j] = (f32x4){0.f, 0.f, 0.f, 0.f};

    // prologue: stage tile 0 into buf 0, drain, barrier
    __builtin_amdgcn_global_load_lds(GLP(Ap0), LDP(&As[0][wd]),        16, 0, 0);
    __builtin_amdgcn_global_load_lds(GLP(Ap1), LDP(&As[0][4096 + wd]), 16, 0, 0);
    __builtin_amdgcn_global_load_lds(GLP(Bp ), LDP(&Bs[0][wd]),        16, 0, 0);
    __syncthreads();

    for (int k0 = 0; k0 < K; k0 += 32) {
        const int cur = (k0 >> 5) & 1;
        if (k0 + 32 < K) {
            const int nxt = cur ^ 1;
            __builtin_amdgcn_global_load_lds(GLP(Ap0 + k0 + 32), LDP(&As[nxt][wd]),        16, 0, 0);
            __builtin_amdgcn_global_load_lds(GLP(Ap1 + k0 + 32), LDP(&As[nxt][4096 + wd]), 16, 0, 0);
            __builtin_amdgcn_global_load_lds(GLP(Bp  + k0 + 32), LDP(&Bs[nxt][wd]),        16, 0, 0);
        }

        bf16x8 af[4], bf[4];
#pragma unroll
        for (int mt = 0; mt < 4; ++mt)
            af[mt] = *(const bf16x8*)(&As[cur][(mw + mt * 16 + c) * 32 + q * 8]);
#pragma unroll
        for (int nt = 0; nt < 4; ++nt)
            bf[nt] = *(const bf16x8*)(&Bs[cur][(nw + nt * 16 + c) * 32 + q * 8]);

#pragma unroll
        for (int mt = 0; mt < 4; ++mt)
#pragma unroll
            for (int nt = 0; nt < 4; ++nt)
                acc[mt][nt] = __builtin_amdgcn_mfma_f32_16x16x32_bf16(af[mt], bf[nt], acc[mt][nt], 0, 0, 0);

        __syncthreads();   // drains next-tile vmcnt + this tile's lgkm; barrier
    }

#pragma unroll
    for (int nt = 0; nt < 4; ++nt) {
        const int col = colTile + nw + nt * 16 + c;
        const float bv = bias ? bias[col] : 0.f;
#pragma unroll
        for (int mt = 0; mt < 4; ++mt) {
#pragma unroll
            for (int r = 0; r < 4; ++r) {
                const int row = rowTile + mw + mt * 16 + q * 4 + r;
                float v = acc[mt][nt][r] + bv;
                if (do_gelu) {
                    const float y2 = fminf(1.5957691216057308f * v * (1.f + 0.044715f * v * v), 80.f);
                    const float e  = __expf(y2);
                    v = v * e * fast_rcp(e + 1.f);
                }
                if (res) v += res[(size_t)row * N + col];
                store_out(&C[(size_t)row * N + col], v);
            }
        }
    }
}

// ---------------------------------------------------------------------------
// Flash attention v5 (unchanged from round 3 — verified):
// swapped QK^T, in-register P, exp2-folded softmax, l-via-ones-MFMA,
// pre-transposed V, QB=256, KB=64, T14 reg-staged prefetch, T5 setprio.
// ---------------------------------------------------------------------------
#define KB  64
#define QB  256
#define KTP 72
#define VTP 72
#define NT  (SEQ / KB)
// -M0 * log2(e), M0 = 8
#define NEG_M0_LOG2E  (-11.541560327111707f)
// 0.125 * log2(e)
#define QSCALE_LOG2E  (0.18033688011112043f)

__global__ __launch_bounds__(256, 2) void flash_attn_kernel(
    const __hip_bfloat16* __restrict__ qkv,
    __hip_bfloat16* __restrict__ out)
{
    const int tid  = threadIdx.x;
    const int w    = tid >> 6;
    const int lane = tid & 63;
    const int quad = lane >> 4;
    const int c    = lane & 15;

    const int h = blockIdx.y;
    const int b = blockIdx.z;
    const size_t base = (size_t)b * SEQ;
    const int qbase = blockIdx.x * QB + w * 64;

    __shared__ __align__(16) __bf16 Kt[KB * KTP];   // [key][d] pitch 72
    __shared__ __align__(16) __bf16 Vt[DH * VTP];   // [d][pos(key)] pitch 72

    const __bf16* qkvb = (const __bf16*)qkv;

    // Q fragments (B-operand of swapped QK^T): lane -> query qbase+qg*16+c,
    // d = kk*32 + quad*8 + j. Pre-scaled by 0.125*log2(e).
    bf16x8 aq[4][2];
#pragma unroll
    for (int qg = 0; qg < 4; ++qg)
#pragma unroll
        for (int kk = 0; kk < 2; ++kk) {
            bf16x8 t = *(const bf16x8*)(qkvb + (base + qbase + qg * 16 + c) * QKV3
                                        + h * DH + kk * 32 + quad * 8);
#pragma unroll
            for (int j = 0; j < 8; ++j) aq[qg][kk][j] = (__bf16)(QSCALE_LOG2E * (float)t[j]);
        }

    bf16x8 onesv;
#pragma unroll
    for (int j = 0; j < 8; ++j) onesv[j] = (__bf16)1.0f;

    f32x4 o[4][4];
#pragma unroll
    for (int qg = 0; qg < 4; ++qg)
#pragma unroll
        for (int ch = 0; ch < 4; ++ch) o[qg][ch] = (f32x4){0.f, 0.f, 0.f, 0.f};
    f32x4 ol[4] = {{0,0,0,0},{0,0,0,0},{0,0,0,0},{0,0,0,0}};

    // K staging map: thread -> rows sR, sR+32; d-chunk sD (8 wide), vector.
    const int sR = tid >> 3;          // 0..31
    const int sD = (tid & 7) * 8;     // 0..56
    const __bf16* Kg = qkvb + (base + sR) * QKV3 + DIM + h * DH + sD;

    // V gather map: thread -> key octet vm (rows 8vm..8vm+7), d-pair d0,d0+1.
    const int vm = tid & 7;
    const int d0 = (tid >> 3) * 2;    // 0..62
    const __bf16* Vg = qkvb + (base + 8 * vm) * QKV3 + 2 * DIM + h * DH + d0;
    const int bpos = 32 * (vm >> 2) + 16 * (vm & 1) + 4 * ((vm >> 1) & 1);

    // T14 prologue: stage tile 0 into registers
    bf16x8 kA, kB_;
    unsigned vv[8];
    kA  = *(const bf16x8*)(Kg);
    kB_ = *(const bf16x8*)(Kg + (size_t)32 * QKV3);
#pragma unroll
    for (int j = 0; j < 8; ++j)
        vv[j] = *(const unsigned*)(Vg + (size_t)j * QKV3);

    for (int kt = 0; kt < NT; ++kt) {
        // ---- write staged registers to LDS (all vector writes)
        *(bf16x8*)(&Kt[sR * KTP + sD])        = kA;
        *(bf16x8*)(&Kt[(sR + 32) * KTP + sD]) = kB_;
        {
            const unsigned lo01 = (vv[0] & 0xFFFFu) | (vv[1] << 16);
            const unsigned lo23 = (vv[2] & 0xFFFFu) | (vv[3] << 16);
            const unsigned lo45 = (vv[4] & 0xFFFFu) | (vv[5] << 16);
            const unsigned lo67 = (vv[6] & 0xFFFFu) | (vv[7] << 16);
            const unsigned hi01 = (vv[0] >> 16) | (vv[1] & 0xFFFF0000u);
            const unsigned hi23 = (vv[2] >> 16) | (vv[3] & 0xFFFF0000u);
            const unsigned hi45 = (vv[4] >> 16) | (vv[5] & 0xFFFF0000u);
            const unsigned hi67 = (vv[6] >> 16) | (vv[7] & 0xFFFF0000u);
            *(u32x2*)(&Vt[(d0    ) * VTP + bpos])     = (u32x2){lo01, lo23};
            *(u32x2*)(&Vt[(d0    ) * VTP + bpos + 8]) = (u32x2){lo45, lo67};
            *(u32x2*)(&Vt[(d0 + 1) * VTP + bpos])     = (u32x2){hi01, hi23};
            *(u32x2*)(&Vt[(d0 + 1) * VTP + bpos + 8]) = (u32x2){hi45, hi67};
        }
        __syncthreads();

        // ---- T14: issue next tile's global loads now; consumed next iter
        if (kt + 1 < NT) {
            const size_t koff = (size_t)(kt + 1) * KB * QKV3;
            kA  = *(const bf16x8*)(Kg + koff);
            kB_ = *(const bf16x8*)(Kg + koff + (size_t)32 * QKV3);
#pragma unroll
            for (int j = 0; j < 8; ++j)
                vv[j] = *(const unsigned*)(Vg + koff + (size_t)j * QKV3);
        }

        // ---- K fragments (shared across all 4 query groups)
        bf16x8 kf[4][2];
#pragma unroll
        for (int kg = 0; kg < 4; ++kg)
#pragma unroll
            for (int kk = 0; kk < 2; ++kk)
                kf[kg][kk] = *(const bf16x8*)(&Kt[(kg * 16 + c) * KTP + kk * 32 + quad * 8]);

        // ---- QK^T (swapped) + softmax + in-register P, per query group
        bf16x8 ap[4][2];
#pragma unroll
        for (int qg = 0; qg < 4; ++qg) {
            f32x4 st[4];
#pragma unroll
            for (int kg = 0; kg < 4; ++kg)
                st[kg] = (f32x4){NEG_M0_LOG2E, NEG_M0_LOG2E, NEG_M0_LOG2E, NEG_M0_LOG2E};
            __builtin_amdgcn_s_setprio(1);
#pragma unroll
            for (int kg = 0; kg < 4; ++kg)
#pragma unroll
                for (int kk = 0; kk < 2; ++kk)
                    st[kg] = __builtin_amdgcn_mfma_f32_16x16x32_bf16(kf[kg][kk], aq[qg][kk], st[kg], 0, 0, 0);
            __builtin_amdgcn_s_setprio(0);

#pragma unroll
            for (int kg = 0; kg < 4; ++kg)
#pragma unroll
                for (int r = 0; r < 4; ++r)
                    ap[qg][kg >> 1][(kg & 1) * 4 + r] = (__bf16)fast_exp2(st[kg][r]);
        }

        // ---- PV (+ l-accumulation via ones-fragment MFMA)
        __builtin_amdgcn_s_setprio(1);
#pragma unroll
        for (int qg = 0; qg < 4; ++qg) {
            ol[qg] = __builtin_amdgcn_mfma_f32_16x16x32_bf16(ap[qg][0], onesv, ol[qg], 0, 0, 0);
            ol[qg] = __builtin_amdgcn_mfma_f32_16x16x32_bf16(ap[qg][1], onesv, ol[qg], 0, 0, 0);
        }
#pragma unroll
        for (int h2 = 0; h2 < 2; ++h2)
#pragma unroll
            for (int ch = 0; ch < 4; ++ch) {
                bf16x8 bv = *(const bf16x8*)(&Vt[(ch * 16 + c) * VTP + h2 * 32 + quad * 8]);
#pragma unroll
                for (int qg = 0; qg < 4; ++qg)
                    o[qg][ch] = __builtin_amdgcn_mfma_f32_16x16x32_bf16(ap[qg][h2], bv, o[qg][ch], 0, 0, 0);
            }
        __builtin_amdgcn_s_setprio(0);
        __syncthreads();
    }

    // ---- epilogue: ol[qg][r] = l for query quad*4+r of group qg (lane-local).
#pragma unroll
    for (int qg = 0; qg < 4; ++qg) {
#pragma unroll
        for (int r = 0; r < 4; ++r) {
            const float inv = 1.f / ol[qg][r];
            const size_t row = base + qbase + qg * 16 + quad * 4 + r;
#pragma unroll
            for (int ch = 0; ch < 4; ++ch)
                out[row * DIM + h * DH + ch * 16 + c] = __float2bfloat16(o[qg][ch][r] * inv);
        }
    }
}

// ---------------------------------------------------------------------------
// Launch. Workspace plan (peak 72 MiB):
//   X    [0,16):  bf16 8192x1024 — xn1 -> attnout -> xn2
//   wT   [16,24): bf16 transposed-weight slot, recycled 6x
//   qkv  [24,72): bf16 8192x3072 (dead after flash)
//   hdn  [24,56): bf16 8192x2048 (MLP half, reuses dead qkv; recycled 2x)
//   x1 lives in d_out (fp32); MLP split in halves, final GEMM accumulates
//   in-place.
// ---------------------------------------------------------------------------
extern "C" void kernel_launch(void* const* d_in, const int* in_sizes, int n_in,
                              void* d_out, int out_size, void* d_ws, size_t ws_size,
                              hipStream_t stream)
{
    const float* x     = (const float*)d_in[0];
    const float* ln1_g = (const float*)d_in[1];
    const float* ln1_b = (const float*)d_in[2];
    const float* w_qkv = (const float*)d_in[3];
    const float* w_out = (const float*)d_in[4];
    const float* b_out = (const float*)d_in[5];
    const float* ln2_g = (const float*)d_in[6];
    const float* ln2_b = (const float*)d_in[7];
    const float* w1    = (const float*)d_in[8];
    const float* b1    = (const float*)d_in[9];
    const float* w2    = (const float*)d_in[10];
    const float* b2    = (const float*)d_in[11];
    float* out = (float*)d_out;

    char* ws = (char*)d_ws;
    const size_t MiB = 1024 * 1024;
    __hip_bfloat16* X   = (__hip_bfloat16*)(ws);
    __bf16*         wT  = (__bf16*)(ws + 16 * MiB);
    __hip_bfloat16* qkv = (__hip_bfloat16*)(ws + 24 * MiB);
    __bf16*         hdn = (__bf16*)(ws + 24 * MiB);

    dim3 blk(256);
    dim3 blk512(512);

    // 1. wqkvT
    transpose_w_kernel<<<dim3(DIM / 32, QKV3 / 32), blk, 0, stream>>>(w_qkv, wT, QKV3, 0, 0, DIM);
    // 2. xn1 = LN1(x)
    ln_kernel<<<dim3(ROWS), blk, 0, stream>>>(x, ln1_g, ln1_b, X);
    // 3. qkv = xn1 @ w_qkv
    gemm_bt_kernel<__hip_bfloat16><<<dim3(QKV3 / 128, ROWS / 256), blk512, 0, stream>>>(
        (const __bf16*)X, wT, nullptr, nullptr, qkv, ROWS, QKV3, DIM, 0);
    // 4. attnout = flash_attention(qkv) -> X
    flash_attn_kernel<<<dim3(SEQ / QB, HEADS, BATCH), blk, 0, stream>>>(qkv, X);
    // 5. woutT
    transpose_w_kernel<<<dim3(DIM / 32, DIM / 32), blk, 0, stream>>>(w_out, wT, DIM, 0, 0, DIM);
    // 6. x1 = x + attnout @ w_out + b_out -> d_out
    gemm_bt_kernel<float><<<dim3(DIM / 128, ROWS / 256), blk512, 0, stream>>>(
        (const __bf16*)X, wT, b_out, x, out, ROWS, DIM, DIM, 0);
    // 7. xn2 = LN2(x1) -> X
    ln_kernel<<<dim3(ROWS), blk, 0, stream>>>(out, ln2_g, ln2_b, X);

    // MLP half A
    transpose_w_kernel<<<dim3(DIM / 32, 2048 / 32), blk, 0, stream>>>(w1, wT, MLP, 0, 0, DIM);
    gemm_bt_kernel<__hip_bfloat16><<<dim3(2048 / 128, ROWS / 256), blk512, 0, stream>>>(
        (const __bf16*)X, wT, b1, nullptr, (__hip_bfloat16*)hdn, ROWS, 2048, DIM, 1);
    transpose_w_kernel<<<dim3(2048 / 32, DIM / 32), blk, 0, stream>>>(w2, wT, DIM, 0, 0, 2048);
    gemm_bt_kernel<float><<<dim3(DIM / 128, ROWS / 256), blk512, 0, stream>>>(
        hdn, wT, b2, out, out, ROWS, DIM, 2048, 0);

    // MLP half B
    transpose_w_kernel<<<dim3(DIM / 32, 2048 / 32), blk, 0, stream>>>(w1, wT, MLP, 0, 2048, DIM);
    gemm_bt_kernel<__hip_bfloat16><<<dim3(2048 / 128, ROWS / 256), blk512, 0, stream>>>(
        (const __bf16*)X, wT, b1 + 2048, nullptr, (__hip_bfloat16*)hdn, ROWS, 2048, DIM, 1);
    transpose_w_kernel<<<dim3(2048 / 32, DIM / 32), blk, 0, stream>>>(w2, wT, DIM, 2048, 0, 2048);
    gemm_bt_kernel<float><<<dim3(DIM / 128, ROWS / 256), blk512, 0, stream>>>(
        hdn, wT, nullptr, out, out, ROWS, DIM, 2048, 0);
}